// Round 1
// baseline (6764.643 us; speedup 1.0000x reference)
//
#include <hip/hip_runtime.h>
#include <stdint.h>

#define H_DIM   1024
#define G3      3072
#define EMB     50
#define TSTEPS  100
#define NB      4096
#define NLABEL  15

typedef __bf16 bf16x8 __attribute__((ext_vector_type(8)));
typedef float  f32x4  __attribute__((ext_vector_type(4)));

__device__ inline uint16_t f2bf(float f) {
  uint32_t u = __builtin_bit_cast(uint32_t, f);
  u += 0x7FFFu + ((u >> 16) & 1u);   // round-to-nearest-even
  return (uint16_t)(u >> 16);
}

__device__ inline void gld16(const void* g, void* l) {
  __builtin_amdgcn_global_load_lds(
      (const __attribute__((address_space(1))) uint32_t*)g,
      (__attribute__((address_space(3))) uint32_t*)l, 16, 0, 0);
}

// ---------------- prep kernels ----------------

// rec_kernel [1024][3072] f32  ->  recT [3072][1024] bf16 (B^T layout)
__global__ __launch_bounds__(256) void prep_recT(const float* __restrict__ rec,
                                                 uint16_t* __restrict__ recT) {
  __shared__ uint16_t st[64][72];
  const int n0 = blockIdx.x * 64;   // over 3072
  const int k0 = blockIdx.y * 64;   // over 1024
  const int tid = threadIdx.x;
#pragma unroll
  for (int i = 0; i < 16; ++i) {
    int idx = tid + i * 256;
    int r = idx >> 6;    // k offset
    int c = idx & 63;    // n offset
    st[c][r] = f2bf(rec[(size_t)(k0 + r) * G3 + n0 + c]);
  }
  __syncthreads();
#pragma unroll
  for (int i = 0; i < 16; ++i) {
    int idx = tid + i * 256;
    int r = idx >> 6;    // n offset
    int c = idx & 63;    // k offset
    recT[(size_t)(n0 + r) * H_DIM + k0 + c] = st[r][c];
  }
}

// kernel [50][3072] f32 -> kerT [3072][64] bf16, zero-padded k in [50,64)
__global__ __launch_bounds__(256) void prep_kerT(const float* __restrict__ ker,
                                                 uint16_t* __restrict__ kerT) {
  int n = blockIdx.x * 4 + (threadIdx.x >> 6);   // 0..3071
  int k = threadIdx.x & 63;
  float v = (k < EMB) ? ker[(size_t)k * G3 + n] : 0.f;
  kerT[(size_t)n * 64 + k] = f2bf(v);
}

// embt [100][4096][64] bf16 = emb_table[x[b,t]], zero-padded cols [50,64)
__global__ __launch_bounds__(256) void prep_embt(const int* __restrict__ x,
                                                 const float* __restrict__ tab,
                                                 uint16_t* __restrict__ embt) {
  int g = blockIdx.x * 4 + (threadIdx.x >> 6);   // t*4096 + b
  int t = g >> 12;
  int b = g & 4095;
  int k = threadIdx.x & 63;
  int idx = x[b * TSTEPS + t];
  float v = (k < EMB) ? tab[(size_t)idx * EMB + k] : 0.f;
  embt[(size_t)g * 64 + k] = f2bf(v);
}

// ---------------- fused GRU step ----------------
// grid (32,16), block 256. Tile: 128 batch rows x 64 hidden cols, all 3 gates.
__global__ __launch_bounds__(256) void gru_step_kernel(
    const uint16_t* __restrict__ hb_prev,   // [4096][1024] bf16
    float* __restrict__ hf,                 // [4096][1024] f32 (in-place)
    uint16_t* __restrict__ hb_next,         // [4096][1024] bf16
    const uint16_t* __restrict__ recT,      // [3072][1024] bf16
    const uint16_t* __restrict__ kerT,      // [3072][64]   bf16
    const uint16_t* __restrict__ embt,      // [4096][64]   bf16 (this step)
    const float* __restrict__ bias_i,       // [3072]
    const float* __restrict__ bias_r) {     // [3072]
  __shared__ __align__(16) uint16_t sA[128 * 64];
  __shared__ __align__(16) uint16_t sB[3][64 * 64];

  const int tid  = threadIdx.x;
  const int lane = tid & 63;
  const int wid  = tid >> 6;
  const int wm   = wid >> 1;   // wave row 0..1
  const int wn   = wid & 1;    // wave col 0..1
  const int r0   = blockIdx.x * 128;
  const int j0   = blockIdx.y * 64;

  f32x4 accZ[4][2], accR[4][2], accH[4][2], accX[4][2];
#pragma unroll
  for (int m = 0; m < 4; ++m)
#pragma unroll
    for (int n = 0; n < 2; ++n) {
      accZ[m][n] = (f32x4){0.f, 0.f, 0.f, 0.f};
      accR[m][n] = (f32x4){0.f, 0.f, 0.f, 0.f};
      accH[m][n] = (f32x4){0.f, 0.f, 0.f, 0.f};
      accX[m][n] = (f32x4){0.f, 0.f, 0.f, 0.f};
    }

  // -------- recurrent part: K = 1024 --------
  for (int kt = 0; kt < 16; ++kt) {
    const int k0 = kt * 64;
#pragma unroll
    for (int i = 0; i < 4; ++i) {            // A tile 128x64 = 16 KB
      int q   = wid * 4 + i;
      int row = q * 8 + (lane >> 3);
      int col = (lane & 7) * 8;
      gld16(hb_prev + (size_t)(r0 + row) * H_DIM + k0 + col,
            sA + q * 512 + lane * 8);
    }
#pragma unroll
    for (int i = 0; i < 6; ++i) {            // 3 B panels, 8 KB each
      int c = wid * 6 + i;
      int g = c >> 3, q = c & 7;
      int n  = q * 8 + (lane >> 3);
      int kk = (lane & 7) * 8;
      gld16(recT + (size_t)(g * H_DIM + j0 + n) * H_DIM + k0 + kk,
            &sB[g][q * 512 + lane * 8]);
    }
    __syncthreads();
#pragma unroll
    for (int ks = 0; ks < 2; ++ks) {
      bf16x8 af[4];
#pragma unroll
      for (int mf = 0; mf < 4; ++mf)
        af[mf] = *reinterpret_cast<const bf16x8*>(
            sA + (wm * 64 + mf * 16 + (lane & 15)) * 64 + ks * 32 + (lane >> 4) * 8);
#pragma unroll
      for (int nf = 0; nf < 2; ++nf) {
        int nn = wn * 32 + nf * 16 + (lane & 15);
        int bo = nn * 64 + ks * 32 + (lane >> 4) * 8;
        bf16x8 bz = *reinterpret_cast<const bf16x8*>(&sB[0][bo]);
        bf16x8 br = *reinterpret_cast<const bf16x8*>(&sB[1][bo]);
        bf16x8 bh = *reinterpret_cast<const bf16x8*>(&sB[2][bo]);
#pragma unroll
        for (int mf = 0; mf < 4; ++mf) {
          accZ[mf][nf] = __builtin_amdgcn_mfma_f32_16x16x32_bf16(af[mf], bz, accZ[mf][nf], 0, 0, 0);
          accR[mf][nf] = __builtin_amdgcn_mfma_f32_16x16x32_bf16(af[mf], br, accR[mf][nf], 0, 0, 0);
          accH[mf][nf] = __builtin_amdgcn_mfma_f32_16x16x32_bf16(af[mf], bh, accH[mf][nf], 0, 0, 0);
        }
      }
    }
    __syncthreads();
  }

  // -------- input-projection part: K = 64 (50 padded) --------
  {
#pragma unroll
    for (int i = 0; i < 4; ++i) {
      int q = wid * 4 + i;
      gld16(embt + (size_t)(r0 + q * 8 + (lane >> 3)) * 64 + (lane & 7) * 8,
            sA + q * 512 + lane * 8);
    }
#pragma unroll
    for (int i = 0; i < 6; ++i) {
      int c = wid * 6 + i;
      int g = c >> 3, q = c & 7;
      int n  = q * 8 + (lane >> 3);
      int kk = (lane & 7) * 8;
      gld16(kerT + (size_t)(g * H_DIM + j0 + n) * 64 + kk,
            &sB[g][q * 512 + lane * 8]);
    }
    __syncthreads();
#pragma unroll
    for (int ks = 0; ks < 2; ++ks) {
      bf16x8 af[4];
#pragma unroll
      for (int mf = 0; mf < 4; ++mf)
        af[mf] = *reinterpret_cast<const bf16x8*>(
            sA + (wm * 64 + mf * 16 + (lane & 15)) * 64 + ks * 32 + (lane >> 4) * 8);
#pragma unroll
      for (int nf = 0; nf < 2; ++nf) {
        int nn = wn * 32 + nf * 16 + (lane & 15);
        int bo = nn * 64 + ks * 32 + (lane >> 4) * 8;
        bf16x8 bz = *reinterpret_cast<const bf16x8*>(&sB[0][bo]);
        bf16x8 br = *reinterpret_cast<const bf16x8*>(&sB[1][bo]);
        bf16x8 bh = *reinterpret_cast<const bf16x8*>(&sB[2][bo]);
#pragma unroll
        for (int mf = 0; mf < 4; ++mf) {
          accZ[mf][nf] = __builtin_amdgcn_mfma_f32_16x16x32_bf16(af[mf], bz, accZ[mf][nf], 0, 0, 0);
          accR[mf][nf] = __builtin_amdgcn_mfma_f32_16x16x32_bf16(af[mf], br, accR[mf][nf], 0, 0, 0);
          accX[mf][nf] = __builtin_amdgcn_mfma_f32_16x16x32_bf16(af[mf], bh, accX[mf][nf], 0, 0, 0);
        }
      }
    }
  }

  // -------- epilogue: gates in fp32, write h (f32 master + bf16) --------
#pragma unroll
  for (int nf = 0; nf < 2; ++nf) {
    int col = j0 + wn * 32 + nf * 16 + (lane & 15);
    float b_z = bias_i[col] + bias_r[col];
    float b_r = bias_i[H_DIM + col] + bias_r[H_DIM + col];
    float bih = bias_i[2 * H_DIM + col];
    float brh = bias_r[2 * H_DIM + col];
#pragma unroll
    for (int mf = 0; mf < 4; ++mf) {
#pragma unroll
      for (int q = 0; q < 4; ++q) {
        int row = r0 + wm * 64 + mf * 16 + (lane >> 4) * 4 + q;
        float z  = 1.f / (1.f + __expf(-(accZ[mf][nf][q] + b_z)));
        float rr = 1.f / (1.f + __expf(-(accR[mf][nf][q] + b_r)));
        float pre = accX[mf][nf][q] + bih + rr * (accH[mf][nf][q] + brh);
        float hc  = 2.f / (1.f + __expf(-2.f * pre)) - 1.f;   // tanh
        size_t idx = (size_t)row * H_DIM + col;
        float hold = hf[idx];
        float hnew = z * hold + (1.f - z) * hc;
        hf[idx] = hnew;
        hb_next[idx] = f2bf(hnew);
      }
    }
  }
}

// ---------------- final logits ----------------
__global__ __launch_bounds__(64) void logits_kernel(const float* __restrict__ hf,
                                                    const float* __restrict__ Wd,
                                                    const float* __restrict__ bd,
                                                    float* __restrict__ out) {
  int b = blockIdx.x;
  int l = threadIdx.x;
  float p[NLABEL];
#pragma unroll
  for (int o = 0; o < NLABEL; ++o) p[o] = 0.f;
  for (int kb = 0; kb < 16; ++kb) {
    int k = kb * 64 + l;
    float hv = hf[(size_t)b * H_DIM + k];
#pragma unroll
    for (int o = 0; o < NLABEL; ++o) p[o] += hv * Wd[k * NLABEL + o];
  }
#pragma unroll
  for (int o = 0; o < NLABEL; ++o) {
#pragma unroll
    for (int s = 32; s; s >>= 1) p[o] += __shfl_xor(p[o], s);
  }
  if (l == 0) {
#pragma unroll
    for (int o = 0; o < NLABEL; ++o) out[(size_t)b * NLABEL + o] = p[o] + bd[o];
  }
}

// ---------------- launch ----------------
extern "C" void kernel_launch(void* const* d_in, const int* in_sizes, int n_in,
                              void* d_out, int out_size, void* d_ws, size_t ws_size,
                              hipStream_t stream) {
  const int*   x          = (const int*)d_in[0];
  // d_in[1] = drop_rate (static 0, ignored)
  const float* emb_table  = (const float*)d_in[2];
  const float* kernel_w   = (const float*)d_in[3];
  const float* rec_kernel = (const float*)d_in[4];
  const float* bias_i     = (const float*)d_in[5];
  const float* bias_r     = (const float*)d_in[6];
  const float* Wd         = (const float*)d_in[7];
  const float* bd         = (const float*)d_in[8];
  float* out = (float*)d_out;

  char* ws = (char*)d_ws;
  size_t off = 0;
  auto alloc = [&](size_t bytes) {
    char* p = ws + off;
    off += (bytes + 255) & ~(size_t)255;
    return p;
  };
  float*    hf   = (float*)alloc((size_t)NB * H_DIM * 4);
  uint16_t* hb0  = (uint16_t*)alloc((size_t)NB * H_DIM * 2);
  uint16_t* hb1  = (uint16_t*)alloc((size_t)NB * H_DIM * 2);
  uint16_t* recT = (uint16_t*)alloc((size_t)G3 * H_DIM * 2);
  uint16_t* kerT = (uint16_t*)alloc((size_t)G3 * 64 * 2);
  uint16_t* embt = (uint16_t*)alloc((size_t)TSTEPS * NB * 64 * 2);
  if (off > ws_size) return;  // insufficient workspace -> fail loudly

  hipMemsetAsync(hf, 0, (size_t)NB * H_DIM * 4, stream);
  hipMemsetAsync(hb0, 0, (size_t)NB * H_DIM * 2, stream);

  prep_recT<<<dim3(G3 / 64, H_DIM / 64), 256, 0, stream>>>(rec_kernel, recT);
  prep_kerT<<<G3 / 4, 256, 0, stream>>>(kernel_w, kerT);
  prep_embt<<<TSTEPS * NB / 4, 256, 0, stream>>>(x, emb_table, embt);

  uint16_t* hb[2] = {hb0, hb1};
  for (int t = 0; t < TSTEPS; ++t) {
    gru_step_kernel<<<dim3(NB / 128, H_DIM / 64), 256, 0, stream>>>(
        hb[t & 1], hf, hb[(t + 1) & 1], recT, kerT,
        embt + (size_t)t * NB * 64, bias_i, bias_r);
  }
  logits_kernel<<<NB, 64, 0, stream>>>(hf, Wd, bd, out);
}